// Round 6
// baseline (250.884 us; speedup 1.0000x reference)
//
#include <hip/hip_runtime.h>

#define DIM 768
#define TD 2304
#define NB 8
#define NS 4096
#define NE 6

// ws layout (float offsets)
#define OFF_QCATT  0        // [3][18][768]: rows 0-5 Q, 6-11 P, 12-17 A1 (colmean fold)
#define OFF_A2F    41472    // [2304][6] delta-mean fold
#define OFF_GFULL  55296    // unused (kept for layout stability)
#define OFF_CB0    56640    // [16]
#define OFF_ACCSUM 56656    // [8][6] + pad = 64
#define OFF_CONSTB 56720    // [8][6] + pad
#define OFF_QP     56832    // [3][32768][12]

// ---------------- kernel B: fold all coefficient matrices (+cb0, +accsum zero) ----
__global__ __launch_bounds__(256) void k_fold(
    const float* __restrict__ Wspat, const float* __restrict__ Wtemp,
    const float* __restrict__ Wsync, const float* __restrict__ Wroute,
    const float* __restrict__ Wglob, const float* __restrict__ bglob,
    const float* __restrict__ broute, const float* __restrict__ bspat,
    const float* __restrict__ btemp, const float* __restrict__ bsync,
    float* __restrict__ QcatT, float* __restrict__ A2F,
    float* __restrict__ cb0, float* __restrict__ accsum)
{
    __shared__ float lwr[288 * NE];
    __shared__ float lgf[224 * NE];
    const int t = threadIdx.x;
    for (int i = t; i < 288 * NE; i += 256) lwr[i] = Wroute[i];
    __syncthreads();
    if (t < 224) {
        float g[NE] = {0, 0, 0, 0, 0, 0};
        for (int o = 0; o < 64; ++o) {
            const float w = Wglob[t * 64 + o];
            #pragma unroll
            for (int e = 0; e < NE; ++e) g[e] += w * lwr[(224 + o) * NE + e];
        }
        #pragma unroll
        for (int e = 0; e < NE; ++e) lgf[t * NE + e] = g[e];
    }
    __syncthreads();
    if (blockIdx.x == 0) {
        if (t < NE) {
            float a = broute[t];
            for (int o = 0; o < 64; ++o)  a += bglob[o] * lwr[(224 + o) * NE + t];
            for (int o = 0; o < 128; ++o) a += bspat[o] * (lwr[o * NE + t] + lgf[o * NE + t]);
            for (int o = 0; o < 64; ++o)  a += btemp[o] * (lwr[(128 + o) * NE + t] + lgf[(128 + o) * NE + t]);
            for (int o = 0; o < 32; ++o)  a += bsync[o] * (lwr[(192 + o) * NE + t] + lgf[(192 + o) * NE + t]);
            cb0[t] = a;
        }
        if (t >= 128 && t < 192) accsum[t - 128] = 0.f;
    }

    const int d = blockIdx.x * 256 + t;          // exactly 2304 threads
    const int st = d / DIM, dd = d - st * DIM;

    float p[NE] = {0, 0, 0, 0, 0, 0}, a2[NE] = {0, 0, 0, 0, 0, 0};
    for (int o = 0; o < 64; ++o) {
        const float w = Wtemp[d * 64 + o];
        #pragma unroll
        for (int e = 0; e < NE; ++e) {
            p[e]  += w * lwr[(128 + o) * NE + e];
            a2[e] += w * lgf[(128 + o) * NE + e];
        }
    }
    float qq[NE], a1[NE];
    #pragma unroll
    for (int e = 0; e < NE; ++e) { qq[e] = p[e]; a1[e] = 0.f; }
    for (int o = 0; o < 128; ++o) {
        const float w = Wspat[d * 128 + o];
        #pragma unroll
        for (int e = 0; e < NE; ++e) {
            qq[e] += w * lwr[o * NE + e];
            a1[e] += w * lgf[o * NE + e];
        }
    }
    if (st != 0) {
        const float sg = (st == 1) ? 1.f : -1.f;
        for (int o = 0; o < 32; ++o) {
            const float w = sg * Wsync[dd * 32 + o];
            #pragma unroll
            for (int e = 0; e < NE; ++e) {
                qq[e] += w * lwr[(192 + o) * NE + e];
                a1[e] += w * lgf[(192 + o) * NE + e];
            }
        }
    }
    #pragma unroll
    for (int e = 0; e < NE; ++e) {
        QcatT[(st * 18 + e) * DIM + dd]      = qq[e];
        QcatT[(st * 18 + 6 + e) * DIM + dd]  = p[e];
        QcatT[(st * 18 + 12 + e) * DIM + dd] = a1[e];
        A2F[d * NE + e] = a2[e];
    }
}

// ---------------- kernel C: main streaming pass ----------------
// grid = 8b * 3st * 64rg = 1536 blocks; 256 thr = 4 waves, all over the same
// 64 rows. Wave w computes outputs [3w,3w+3) of the 12 (Q0-5,P0-5).
// Lane: half=l>>5 (row parity within a 2-row iteration), c32=l&31; lane owns
// 24 cols (6 float4 at stride 128). 18 coef float4 resident in registers.
// Reduction: 5-step 32-lane butterfly covers BOTH rows at once (15 shfl/2 rows).
// Waves 0/1 also accumulate column sums (quads 0-2 / 3-5) for the global path.

#define D4(ACC, V, C) ACC += V.x*C.x; ACC += V.y*C.y; ACC += V.z*C.z; ACC += V.w*C.w;

#define LD6(B0, B1, B2, B3, B4, B5, P)          \
    B0 = *(const float4*)(P);                   \
    B1 = *(const float4*)((P) + 128);           \
    B2 = *(const float4*)((P) + 256);           \
    B3 = *(const float4*)((P) + 384);           \
    B4 = *(const float4*)((P) + 512);           \
    B5 = *(const float4*)((P) + 640);

#define RED32(V)                    \
    V += __shfl_xor(V, 1, 64);      \
    V += __shfl_xor(V, 2, 64);      \
    V += __shfl_xor(V, 4, 64);      \
    V += __shfl_xor(V, 8, 64);      \
    V += __shfl_xor(V, 16, 64);

#define RED64(V) RED32(V) V += __shfl_xor(V, 32, 64);

#define CMP(B0, B1, B2, B3, B4, B5, RO) {                                   \
    float q0 = 0.f, q1 = 0.f, q2 = 0.f;                                     \
    D4(q0,B0,c00) D4(q0,B1,c01) D4(q0,B2,c02)                               \
    D4(q0,B3,c03) D4(q0,B4,c04) D4(q0,B5,c05)                               \
    D4(q1,B0,c10) D4(q1,B1,c11) D4(q1,B2,c12)                               \
    D4(q1,B3,c13) D4(q1,B4,c14) D4(q1,B5,c15)                               \
    D4(q2,B0,c20) D4(q2,B1,c21) D4(q2,B2,c22)                               \
    D4(q2,B3,c23) D4(q2,B4,c24) D4(q2,B5,c25)                               \
    if (w == 0) {                                                           \
        s0 += B0.x; s1 += B0.y; s2  += B0.z; s3  += B0.w;                   \
        s4 += B1.x; s5 += B1.y; s6  += B1.z; s7  += B1.w;                   \
        s8 += B2.x; s9 += B2.y; s10 += B2.z; s11 += B2.w;                   \
    } else if (w == 1) {                                                    \
        s0 += B3.x; s1 += B3.y; s2  += B3.z; s3  += B3.w;                   \
        s4 += B4.x; s5 += B4.y; s6  += B4.z; s7  += B4.w;                   \
        s8 += B5.x; s9 += B5.y; s10 += B5.z; s11 += B5.w;                   \
    }                                                                       \
    RED32(q0) RED32(q1) RED32(q2)                                           \
    if ((l & 31) == 0) {                                                    \
        float* dst_ = qpb + (RO) * 12;                                      \
        dst_[0] = q0; dst_[1] = q1; dst_[2] = q2;                           \
    } }

#define GAE(GA, E) {                                                        \
    const float4 u0 = *(const float4*)(cab + (E) * DIM);                    \
    const float4 u1 = *(const float4*)(cab + (E) * DIM + 128);              \
    const float4 u2 = *(const float4*)(cab + (E) * DIM + 256);              \
    GA = s0*u0.x + s1*u0.y + s2*u0.z + s3*u0.w                              \
       + s4*u1.x + s5*u1.y + s6*u1.z + s7*u1.w                              \
       + s8*u2.x + s9*u2.y + s10*u2.z + s11*u2.w; }

__global__ __launch_bounds__(256, 3) void k_main(
    const float* __restrict__ xt, const float* __restrict__ xa, const float* __restrict__ xv,
    const float* __restrict__ QcatT, float* __restrict__ accsum, float* __restrict__ qp)
{
    const int t = threadIdx.x;
    const int w = t >> 6, l = t & 63;
    const int half = l >> 5, c32 = l & 31;
    const int bid = blockIdx.x;
    const int rg = bid & 63;
    const int st = (bid >> 6) % 3;
    const int bb = bid / 192;

    const float* X = (st == 0) ? xt : ((st == 1) ? xa : xv);
    const int row0 = rg * 64;
    const float* xp = X + (size_t)(bb * NS + row0 + half) * DIM + c32 * 4;
    const float* cqb = QcatT + (st * 18 + 3 * w) * DIM + c32 * 4;
    float* qpb = qp + ((size_t)(st * NB + bb) * NS + row0 + half) * 12 + 3 * w;

    const float4 c00 = *(const float4*)(cqb + 0 * DIM);
    const float4 c01 = *(const float4*)(cqb + 0 * DIM + 128);
    const float4 c02 = *(const float4*)(cqb + 0 * DIM + 256);
    const float4 c03 = *(const float4*)(cqb + 0 * DIM + 384);
    const float4 c04 = *(const float4*)(cqb + 0 * DIM + 512);
    const float4 c05 = *(const float4*)(cqb + 0 * DIM + 640);
    const float4 c10 = *(const float4*)(cqb + 1 * DIM);
    const float4 c11 = *(const float4*)(cqb + 1 * DIM + 128);
    const float4 c12 = *(const float4*)(cqb + 1 * DIM + 256);
    const float4 c13 = *(const float4*)(cqb + 1 * DIM + 384);
    const float4 c14 = *(const float4*)(cqb + 1 * DIM + 512);
    const float4 c15 = *(const float4*)(cqb + 1 * DIM + 640);
    const float4 c20 = *(const float4*)(cqb + 2 * DIM);
    const float4 c21 = *(const float4*)(cqb + 2 * DIM + 128);
    const float4 c22 = *(const float4*)(cqb + 2 * DIM + 256);
    const float4 c23 = *(const float4*)(cqb + 2 * DIM + 384);
    const float4 c24 = *(const float4*)(cqb + 2 * DIM + 512);
    const float4 c25 = *(const float4*)(cqb + 2 * DIM + 640);

    float s0 = 0, s1 = 0, s2 = 0, s3 = 0, s4 = 0, s5 = 0;
    float s6 = 0, s7 = 0, s8 = 0, s9 = 0, s10 = 0, s11 = 0;

    float4 a0, a1, a2, a3, a4, a5, b0, b1, b2, b3, b4, b5;
    LD6(a0, a1, a2, a3, a4, a5, xp)
    LD6(b0, b1, b2, b3, b4, b5, xp + 2 * DIM)

    for (int i = 0; i < 32; i += 2) {
        CMP(a0, a1, a2, a3, a4, a5, 2 * i)
        if (i + 2 < 32) { LD6(a0, a1, a2, a3, a4, a5, xp + 4 * DIM) }
        CMP(b0, b1, b2, b3, b4, b5, 2 * i + 2)
        if (i + 3 < 32) { LD6(b0, b1, b2, b3, b4, b5, xp + 6 * DIM) }
        xp += 4 * DIM;
    }

    // global-path epilogue: waves 0/1 project their column sums onto A1
    if (w < 2) {
        const float* cab = QcatT + (st * 18 + 12) * DIM + c32 * 4 + 3 * w * 128;
        float ga0, ga1, ga2, ga3, ga4, ga5;
        GAE(ga0, 0) GAE(ga1, 1) GAE(ga2, 2)
        GAE(ga3, 3) GAE(ga4, 4) GAE(ga5, 5)
        RED64(ga0) RED64(ga1) RED64(ga2)
        RED64(ga3) RED64(ga4) RED64(ga5)
        if (l == 0) {
            atomicAdd(&accsum[bb * NE + 0], ga0);
            atomicAdd(&accsum[bb * NE + 1], ga1);
            atomicAdd(&accsum[bb * NE + 2], ga2);
            atomicAdd(&accsum[bb * NE + 3], ga3);
            atomicAdd(&accsum[bb * NE + 4], ga4);
            atomicAdd(&accsum[bb * NE + 5], ga5);
        }
    }
}

// ---------------- kernel D: per-batch global constant ----------------
__global__ __launch_bounds__(256) void k_const(
    const float* __restrict__ xt, const float* __restrict__ xa, const float* __restrict__ xv,
    const float* __restrict__ accsum, const float* __restrict__ A2F,
    const float* __restrict__ cb0, float* __restrict__ constb)
{
    const int b = blockIdx.x, t = threadIdx.x;
    const float* Xs[3] = { xt, xa, xv };
    float acc[NE] = {0, 0, 0, 0, 0, 0};
    for (int f = t; f < TD; f += 256) {
        const int st = f / DIM, dd = f - st * DIM;
        const float* Xp = Xs[st] + (size_t)b * NS * DIM;
        const float dm = Xp[(size_t)(NS - 1) * DIM + dd] - Xp[dd];
        const float* Ap = A2F + f * NE;
        #pragma unroll
        for (int e = 0; e < NE; ++e) acc[e] += dm * Ap[e];
    }
    #pragma unroll
    for (int e = 0; e < NE; ++e)
        for (int m = 1; m < 64; m <<= 1) acc[e] += __shfl_xor(acc[e], m, 64);
    __shared__ float wred[4][NE];
    if ((t & 63) == 0) {
        #pragma unroll
        for (int e = 0; e < NE; ++e) wred[t >> 6][e] = acc[e];
    }
    __syncthreads();
    if (t < NE) {
        const float inv = 1.f / 4096.f;
        const float dsum = wred[0][t] + wred[1][t] + wred[2][t] + wred[3][t];
        constb[b * NE + t] = cb0[t] + accsum[b * NE + t] * inv + dsum * inv;
    }
}

// ---------------- kernel E: combine q - shifted p + const ----------------
__global__ __launch_bounds__(256) void k_add(
    const float* __restrict__ qp, const float* __restrict__ constb, float* __restrict__ out)
{
    const int row = blockIdx.x * 256 + threadIdx.x;   // 32768 rows exact
    const int b = row >> 12, s = row & (NS - 1);
    const int rowp = (s == 0) ? row : row - 1;
    float o[NE];
    #pragma unroll
    for (int e = 0; e < NE; ++e) o[e] = constb[b * NE + e];
    #pragma unroll
    for (int st = 0; st < 3; ++st) {
        const float* qr = qp + ((size_t)st * NB * NS + row) * 12;
        const float* pr = qp + ((size_t)st * NB * NS + rowp) * 12;
        #pragma unroll
        for (int e = 0; e < NE; ++e) o[e] += qr[e] - pr[6 + e];
    }
    float* op = out + (size_t)row * NE;
    #pragma unroll
    for (int e = 0; e < NE; ++e) op[e] = o[e];
}

extern "C" void kernel_launch(void* const* d_in, const int* in_sizes, int n_in,
                              void* d_out, int out_size, void* d_ws, size_t ws_size,
                              hipStream_t stream)
{
    const float* xt     = (const float*)d_in[0];
    const float* xa     = (const float*)d_in[1];
    const float* xv     = (const float*)d_in[2];
    const float* Wspat  = (const float*)d_in[3];
    const float* bspat  = (const float*)d_in[4];
    const float* Wtemp  = (const float*)d_in[5];
    const float* btemp  = (const float*)d_in[6];
    const float* Wsync  = (const float*)d_in[7];
    const float* bsync  = (const float*)d_in[8];
    const float* Wglob  = (const float*)d_in[9];
    const float* bglob  = (const float*)d_in[10];
    const float* Wroute = (const float*)d_in[11];
    const float* broute = (const float*)d_in[12];
    float* out = (float*)d_out;

    float* ws     = (float*)d_ws;
    float* QcatT  = ws + OFF_QCATT;
    float* A2F    = ws + OFF_A2F;
    float* cb0    = ws + OFF_CB0;
    float* accsum = ws + OFF_ACCSUM;
    float* constb = ws + OFF_CONSTB;
    float* qp     = ws + OFF_QP;

    k_fold<<<9, 256, 0, stream>>>(Wspat, Wtemp, Wsync, Wroute, Wglob, bglob,
                                  broute, bspat, btemp, bsync, QcatT, A2F, cb0, accsum);
    k_main<<<1536, 256, 0, stream>>>(xt, xa, xv, QcatT, accsum, qp);
    k_const<<<8, 256, 0, stream>>>(xt, xa, xv, accsum, A2F, cb0, constb);
    k_add<<<128, 256, 0, stream>>>(qp, constb, out);
}

// Round 7
// 230.759 us; speedup vs baseline: 1.0872x; 1.0872x over previous
//
#include <hip/hip_runtime.h>

#define DIM 768
#define TD 2304
#define NB 8
#define NS 4096
#define NE 6

// ws layout (float offsets)
#define OFF_QCATT  0        // [3][18][768]: rows 0-5 Q, 6-11 P, 12-17 A1 (colmean fold)
#define OFF_A2F    41472    // [2304][6] delta-mean fold
#define OFF_CB0    56640    // [16]
#define OFF_ACCSUM 56656    // [8][6] + pad = 64
#define OFF_CONSTB 56720    // [8][6] + pad
#define OFF_QP     56832    // [3][32768][12]

// ---------------- kernel B: fold all coefficient matrices (+cb0, +accsum zero) ----
__global__ __launch_bounds__(256) void k_fold(
    const float* __restrict__ Wspat, const float* __restrict__ Wtemp,
    const float* __restrict__ Wsync, const float* __restrict__ Wroute,
    const float* __restrict__ Wglob, const float* __restrict__ bglob,
    const float* __restrict__ broute, const float* __restrict__ bspat,
    const float* __restrict__ btemp, const float* __restrict__ bsync,
    float* __restrict__ QcatT, float* __restrict__ A2F,
    float* __restrict__ cb0, float* __restrict__ accsum)
{
    __shared__ float lwr[288 * NE];
    __shared__ float lgf[224 * NE];
    const int t = threadIdx.x;
    for (int i = t; i < 288 * NE; i += 256) lwr[i] = Wroute[i];
    __syncthreads();
    if (t < 224) {
        float g[NE] = {0, 0, 0, 0, 0, 0};
        for (int o = 0; o < 64; ++o) {
            const float w = Wglob[t * 64 + o];
            #pragma unroll
            for (int e = 0; e < NE; ++e) g[e] += w * lwr[(224 + o) * NE + e];
        }
        #pragma unroll
        for (int e = 0; e < NE; ++e) lgf[t * NE + e] = g[e];
    }
    __syncthreads();
    if (blockIdx.x == 0) {
        if (t < NE) {
            float a = broute[t];
            for (int o = 0; o < 64; ++o)  a += bglob[o] * lwr[(224 + o) * NE + t];
            for (int o = 0; o < 128; ++o) a += bspat[o] * (lwr[o * NE + t] + lgf[o * NE + t]);
            for (int o = 0; o < 64; ++o)  a += btemp[o] * (lwr[(128 + o) * NE + t] + lgf[(128 + o) * NE + t]);
            for (int o = 0; o < 32; ++o)  a += bsync[o] * (lwr[(192 + o) * NE + t] + lgf[(192 + o) * NE + t]);
            cb0[t] = a;
        }
        if (t >= 128 && t < 192) accsum[t - 128] = 0.f;
    }

    const int d = blockIdx.x * 256 + t;          // exactly 2304 threads
    const int st = d / DIM, dd = d - st * DIM;

    float p[NE] = {0, 0, 0, 0, 0, 0}, a2[NE] = {0, 0, 0, 0, 0, 0};
    for (int o = 0; o < 64; ++o) {
        const float w = Wtemp[d * 64 + o];
        #pragma unroll
        for (int e = 0; e < NE; ++e) {
            p[e]  += w * lwr[(128 + o) * NE + e];
            a2[e] += w * lgf[(128 + o) * NE + e];
        }
    }
    float qq[NE], a1[NE];
    #pragma unroll
    for (int e = 0; e < NE; ++e) { qq[e] = p[e]; a1[e] = 0.f; }
    for (int o = 0; o < 128; ++o) {
        const float w = Wspat[d * 128 + o];
        #pragma unroll
        for (int e = 0; e < NE; ++e) {
            qq[e] += w * lwr[o * NE + e];
            a1[e] += w * lgf[o * NE + e];
        }
    }
    if (st != 0) {
        const float sg = (st == 1) ? 1.f : -1.f;
        for (int o = 0; o < 32; ++o) {
            const float w = sg * Wsync[dd * 32 + o];
            #pragma unroll
            for (int e = 0; e < NE; ++e) {
                qq[e] += w * lwr[(192 + o) * NE + e];
                a1[e] += w * lgf[(192 + o) * NE + e];
            }
        }
    }
    #pragma unroll
    for (int e = 0; e < NE; ++e) {
        QcatT[(st * 18 + e) * DIM + dd]      = qq[e];
        QcatT[(st * 18 + 6 + e) * DIM + dd]  = p[e];
        QcatT[(st * 18 + 12 + e) * DIM + dd] = a1[e];
        A2F[d * NE + e] = a2[e];
    }
}

// ---------------- kernel C: main streaming pass ----------------
// Round-5 geometry: grid = 8b * 3st * 32rblk = 768 blocks; 256 thr = 4 waves
// (2 wave-pairs). Wave pair pr covers rows [row0, row0+64); within a pair,
// wave h=0 computes Q outputs 0-5, h=1 computes P outputs 6-11. Lane l owns
// cols {4l, 4l+256, 4l+512}; 18 coef float4 resident in registers.
// KEY CHANGE vs r5: the row loop is NOT unrolled (#pragma unroll 1) — total
// kernel code ~2.5 KB so it stays resident in the 32 KB per-CU I$.

#define LDR(B0, B1, B2, R) {                        \
    const float* xp_ = xbase + (size_t)(R) * DIM;   \
    B0 = *(const float4*)(xp_);                     \
    B1 = *(const float4*)(xp_ + 256);               \
    B2 = *(const float4*)(xp_ + 512); }

#define DOT3(QV, B0, B1, B2, C0, C1, C2)                                    \
    QV += B0.x * C0.x; QV += B0.y * C0.y; QV += B0.z * C0.z; QV += B0.w * C0.w; \
    QV += B1.x * C1.x; QV += B1.y * C1.y; QV += B1.z * C1.z; QV += B1.w * C1.w; \
    QV += B2.x * C2.x; QV += B2.y * C2.y; QV += B2.z * C2.z; QV += B2.w * C2.w;

#define RED64(V)                    \
    V += __shfl_xor(V, 1, 64);      \
    V += __shfl_xor(V, 2, 64);      \
    V += __shfl_xor(V, 4, 64);      \
    V += __shfl_xor(V, 8, 64);      \
    V += __shfl_xor(V, 16, 64);     \
    V += __shfl_xor(V, 32, 64);

#define CMP(B0, B1, B2, R) {                                \
    float q0 = 0, q1 = 0, q2 = 0, q3 = 0, q4 = 0, q5 = 0;   \
    DOT3(q0, B0, B1, B2, c00, c01, c02)                     \
    DOT3(q1, B0, B1, B2, c10, c11, c12)                     \
    DOT3(q2, B0, B1, B2, c20, c21, c22)                     \
    DOT3(q3, B0, B1, B2, c30, c31, c32)                     \
    DOT3(q4, B0, B1, B2, c40, c41, c42)                     \
    DOT3(q5, B0, B1, B2, c50, c51, c52)                     \
    cs0 += B0.x; cs1 += B0.y; cs2  += B0.z; cs3  += B0.w;   \
    cs4 += B1.x; cs5 += B1.y; cs6  += B1.z; cs7  += B1.w;   \
    cs8 += B2.x; cs9 += B2.y; cs10 += B2.z; cs11 += B2.w;   \
    RED64(q0) RED64(q1) RED64(q2)                           \
    RED64(q3) RED64(q4) RED64(q5)                           \
    if (l == 0) {                                           \
        float* dst_ = qpb + (size_t)(R) * 12;               \
        *(float2*)(dst_ + 0) = make_float2(q0, q1);         \
        *(float2*)(dst_ + 2) = make_float2(q2, q3);         \
        *(float2*)(dst_ + 4) = make_float2(q4, q5);         \
    } }

#define GDOT(GV, C0, C1, C2)                                \
    GV += cs0 * C0.x; GV += cs1 * C0.y; GV += cs2  * C0.z; GV += cs3  * C0.w; \
    GV += cs4 * C1.x; GV += cs5 * C1.y; GV += cs6  * C1.z; GV += cs7  * C1.w; \
    GV += cs8 * C2.x; GV += cs9 * C2.y; GV += cs10 * C2.z; GV += cs11 * C2.w;

__global__ __launch_bounds__(256, 4) void k_main(
    const float* __restrict__ xt, const float* __restrict__ xa, const float* __restrict__ xv,
    const float* __restrict__ QcatT, float* __restrict__ accsum, float* __restrict__ qp)
{
    const int t = threadIdx.x;
    const int w = t >> 6, l = t & 63;
    const int h = w & 1;                 // 0: Q half, 1: P half
    const int pr = w >> 1;               // wave pair -> 64-row slice
    const int bid = blockIdx.x;
    const int rblk = bid & 31;
    const int st = (bid >> 5) % 3;
    const int bb = bid / 96;

    const float* X = (st == 0) ? xt : ((st == 1) ? xa : xv);
    const int row0 = rblk * 128 + pr * 64;
    const float* xbase = X + (size_t)(bb * NS + row0) * DIM + l * 4;
    const float* cqb   = QcatT + (st * 18 + h * 6) * DIM + l * 4;
    float*       qpb   = qp + ((size_t)(st * NB + bb) * NS + row0) * 12 + h * 6;

    // coefficient registers (loop-invariant, resident for whole kernel)
    const float4 c00 = *(const float4*)(cqb + 0 * DIM + 0);
    const float4 c01 = *(const float4*)(cqb + 0 * DIM + 256);
    const float4 c02 = *(const float4*)(cqb + 0 * DIM + 512);
    const float4 c10 = *(const float4*)(cqb + 1 * DIM + 0);
    const float4 c11 = *(const float4*)(cqb + 1 * DIM + 256);
    const float4 c12 = *(const float4*)(cqb + 1 * DIM + 512);
    const float4 c20 = *(const float4*)(cqb + 2 * DIM + 0);
    const float4 c21 = *(const float4*)(cqb + 2 * DIM + 256);
    const float4 c22 = *(const float4*)(cqb + 2 * DIM + 512);
    const float4 c30 = *(const float4*)(cqb + 3 * DIM + 0);
    const float4 c31 = *(const float4*)(cqb + 3 * DIM + 256);
    const float4 c32 = *(const float4*)(cqb + 3 * DIM + 512);
    const float4 c40 = *(const float4*)(cqb + 4 * DIM + 0);
    const float4 c41 = *(const float4*)(cqb + 4 * DIM + 256);
    const float4 c42 = *(const float4*)(cqb + 4 * DIM + 512);
    const float4 c50 = *(const float4*)(cqb + 5 * DIM + 0);
    const float4 c51 = *(const float4*)(cqb + 5 * DIM + 256);
    const float4 c52 = *(const float4*)(cqb + 5 * DIM + 512);

    // per-lane column sums (for the global colmean path)
    float cs0 = 0, cs1 = 0, cs2 = 0, cs3 = 0, cs4 = 0, cs5 = 0;
    float cs6 = 0, cs7 = 0, cs8 = 0, cs9 = 0, cs10 = 0, cs11 = 0;

    float4 xA0, xA1, xA2, xB0, xB1, xB2;
    LDR(xA0, xA1, xA2, 0)
    LDR(xB0, xB1, xB2, 1)

    // guard-free ping-pong body; NOT unrolled -> ~2 KB of loop code (I$-resident)
    #pragma unroll 1
    for (int r = 0; r < 62; r += 2) {
        CMP(xA0, xA1, xA2, r)
        LDR(xA0, xA1, xA2, r + 2)
        CMP(xB0, xB1, xB2, r + 1)
        LDR(xB0, xB1, xB2, r + 3)
    }
    CMP(xA0, xA1, xA2, 62)
    CMP(xB0, xB1, xB2, 63)

    // global-path epilogue: dot colsums with A1 coefs, reduce, atomic
    const float* cab = QcatT + (st * 18 + 12 + h * 3) * DIM + l * 4;
    const float4 A00 = *(const float4*)(cab + 0 * DIM + 0);
    const float4 A01 = *(const float4*)(cab + 0 * DIM + 256);
    const float4 A02 = *(const float4*)(cab + 0 * DIM + 512);
    const float4 A10 = *(const float4*)(cab + 1 * DIM + 0);
    const float4 A11 = *(const float4*)(cab + 1 * DIM + 256);
    const float4 A12 = *(const float4*)(cab + 1 * DIM + 512);
    const float4 A20 = *(const float4*)(cab + 2 * DIM + 0);
    const float4 A21 = *(const float4*)(cab + 2 * DIM + 256);
    const float4 A22 = *(const float4*)(cab + 2 * DIM + 512);

    float g0 = 0, g1 = 0, g2 = 0;
    GDOT(g0, A00, A01, A02)
    GDOT(g1, A10, A11, A12)
    GDOT(g2, A20, A21, A22)
    RED64(g0) RED64(g1) RED64(g2)
    if (l == 0) {
        atomicAdd(&accsum[bb * NE + h * 3 + 0], g0);
        atomicAdd(&accsum[bb * NE + h * 3 + 1], g1);
        atomicAdd(&accsum[bb * NE + h * 3 + 2], g2);
    }
}

// ---------------- kernel D: per-batch global constant ----------------
__global__ __launch_bounds__(256) void k_const(
    const float* __restrict__ xt, const float* __restrict__ xa, const float* __restrict__ xv,
    const float* __restrict__ accsum, const float* __restrict__ A2F,
    const float* __restrict__ cb0, float* __restrict__ constb)
{
    const int b = blockIdx.x, t = threadIdx.x;
    const float* Xs[3] = { xt, xa, xv };
    float acc[NE] = {0, 0, 0, 0, 0, 0};
    for (int f = t; f < TD; f += 256) {
        const int st = f / DIM, dd = f - st * DIM;
        const float* Xp = Xs[st] + (size_t)b * NS * DIM;
        const float dm = Xp[(size_t)(NS - 1) * DIM + dd] - Xp[dd];
        const float* Ap = A2F + f * NE;
        #pragma unroll
        for (int e = 0; e < NE; ++e) acc[e] += dm * Ap[e];
    }
    #pragma unroll
    for (int e = 0; e < NE; ++e)
        for (int m = 1; m < 64; m <<= 1) acc[e] += __shfl_xor(acc[e], m, 64);
    __shared__ float wred[4][NE];
    if ((t & 63) == 0) {
        #pragma unroll
        for (int e = 0; e < NE; ++e) wred[t >> 6][e] = acc[e];
    }
    __syncthreads();
    if (t < NE) {
        const float inv = 1.f / 4096.f;
        const float dsum = wred[0][t] + wred[1][t] + wred[2][t] + wred[3][t];
        constb[b * NE + t] = cb0[t] + accsum[b * NE + t] * inv + dsum * inv;
    }
}

// ---------------- kernel E: combine q - shifted p + const ----------------
__global__ __launch_bounds__(256) void k_add(
    const float* __restrict__ qp, const float* __restrict__ constb, float* __restrict__ out)
{
    const int row = blockIdx.x * 256 + threadIdx.x;   // 32768 rows exact
    const int b = row >> 12, s = row & (NS - 1);
    const int rowp = (s == 0) ? row : row - 1;
    float o[NE];
    #pragma unroll
    for (int e = 0; e < NE; ++e) o[e] = constb[b * NE + e];
    #pragma unroll
    for (int st = 0; st < 3; ++st) {
        const float* qr = qp + ((size_t)st * NB * NS + row) * 12;
        const float* pr = qp + ((size_t)st * NB * NS + rowp) * 12;
        #pragma unroll
        for (int e = 0; e < NE; ++e) o[e] += qr[e] - pr[6 + e];
    }
    float* op = out + (size_t)row * NE;
    #pragma unroll
    for (int e = 0; e < NE; ++e) op[e] = o[e];
}

extern "C" void kernel_launch(void* const* d_in, const int* in_sizes, int n_in,
                              void* d_out, int out_size, void* d_ws, size_t ws_size,
                              hipStream_t stream)
{
    const float* xt     = (const float*)d_in[0];
    const float* xa     = (const float*)d_in[1];
    const float* xv     = (const float*)d_in[2];
    const float* Wspat  = (const float*)d_in[3];
    const float* bspat  = (const float*)d_in[4];
    const float* Wtemp  = (const float*)d_in[5];
    const float* btemp  = (const float*)d_in[6];
    const float* Wsync  = (const float*)d_in[7];
    const float* bsync  = (const float*)d_in[8];
    const float* Wglob  = (const float*)d_in[9];
    const float* bglob  = (const float*)d_in[10];
    const float* Wroute = (const float*)d_in[11];
    const float* broute = (const float*)d_in[12];
    float* out = (float*)d_out;

    float* ws     = (float*)d_ws;
    float* QcatT  = ws + OFF_QCATT;
    float* A2F    = ws + OFF_A2F;
    float* cb0    = ws + OFF_CB0;
    float* accsum = ws + OFF_ACCSUM;
    float* constb = ws + OFF_CONSTB;
    float* qp     = ws + OFF_QP;

    k_fold<<<9, 256, 0, stream>>>(Wspat, Wtemp, Wsync, Wroute, Wglob, bglob,
                                  broute, bspat, btemp, bsync, QcatT, A2F, cb0, accsum);
    k_main<<<768, 256, 0, stream>>>(xt, xa, xv, QcatT, accsum, qp);
    k_const<<<8, 256, 0, stream>>>(xt, xa, xv, accsum, A2F, cb0, constb);
    k_add<<<128, 256, 0, stream>>>(qp, constb, out);
}